// Round 1
// baseline (218.677 us; speedup 1.0000x reference)
//
#include <hip/hip_runtime.h>

#define BB 4
#define SS 1024
#define DD 1024
#define HH 16
#define DKK 64
#define MM (BB*SS)   // 4096

typedef __bf16 bf16;
typedef __bf16 bf16x8 __attribute__((ext_vector_type(8)));
typedef float f32x4 __attribute__((ext_vector_type(4)));

__device__ __forceinline__ f32x4 mfma16(bf16x8 a, bf16x8 b, f32x4 c) {
  return __builtin_amdgcn_mfma_f32_16x16x32_bf16(a, b, c, 0, 0, 0);
}

// ---------------- mask -> bitmask ----------------
// bits[row*32 + w] covers cols [32w, 32w+32) of mask row (row = b*S + q)
__global__ __launch_bounds__(256) void k_mask_bits(const int* __restrict__ mask,
                                                   unsigned* __restrict__ bits) {
  const int row = blockIdx.x;
  const int tid = threadIdx.x;
  const int lane = tid & 63, wv = tid >> 6;
#pragma unroll
  for (int it = 0; it < 4; ++it) {
    const int base = it * 256 + wv * 64;
    const int col = base + lane;
    unsigned long long bal = __ballot(mask[(size_t)row * SS + col] != 0);
    if (lane == 0) {
      bits[(size_t)row * 32 + (base >> 5)] = (unsigned)bal;
      bits[(size_t)row * 32 + (base >> 5) + 1] = (unsigned)(bal >> 32);
    }
  }
}

// ---------------- GEMM  C = A @ W^T ----------------
// A: [Mtot,K] (fp32 or bf16), W: [N,K] fp32, C: [Mtot,N] (bf16 or fp32)
// 128x128 tile, BK=32, 4 waves (2x2), each wave 64x64 out.
template<int AF32, int CF32>
__device__ __forceinline__ void gemm_body(const void* __restrict__ Ap,
                                          const float* __restrict__ Wp,
                                          void* __restrict__ Cp,
                                          int Mtot, int N, int K, int blk) {
  __shared__ bf16 Al[128 * 40];
  __shared__ bf16 Bl[128 * 40];
  const int tid = threadIdx.x;
  const int lane = tid & 63;
  const int l15 = lane & 15, l4 = lane >> 4;
  const int wv = tid >> 6;
  const int nbm = Mtot >> 7;
  const int bm = blk % nbm, bn = blk / nbm;
  const size_t m0 = (size_t)bm << 7, n0 = (size_t)bn << 7;
  const int wr = (wv >> 1) << 6, wc = (wv & 1) << 6;
  const int srow = tid >> 2, scol = (tid & 3) << 3;

  f32x4 acc[4][4];
#pragma unroll
  for (int i = 0; i < 4; ++i)
#pragma unroll
    for (int j = 0; j < 4; ++j) acc[i][j] = f32x4{0.f, 0.f, 0.f, 0.f};

  for (int k0 = 0; k0 < K; k0 += 32) {
#pragma unroll
    for (int c = 0; c < 2; ++c) {
      const int row = (c << 6) + srow;
      bf16x8 av;
      if (AF32) {
        const float* s = (const float*)Ap + (m0 + row) * (size_t)K + k0 + scol;
        f32x4 v0 = *(const f32x4*)s;
        f32x4 v1 = *(const f32x4*)(s + 4);
#pragma unroll
        for (int j = 0; j < 4; ++j) { av[j] = (bf16)v0[j]; av[4 + j] = (bf16)v1[j]; }
      } else {
        av = *(const bf16x8*)((const bf16*)Ap + (m0 + row) * (size_t)K + k0 + scol);
      }
      *(bf16x8*)&Al[row * 40 + scol] = av;

      const float* ws_ = Wp + (n0 + row) * (size_t)K + k0 + scol;
      f32x4 w0 = *(const f32x4*)ws_;
      f32x4 w1 = *(const f32x4*)(ws_ + 4);
      bf16x8 wv8;
#pragma unroll
      for (int j = 0; j < 4; ++j) { wv8[j] = (bf16)w0[j]; wv8[4 + j] = (bf16)w1[j]; }
      *(bf16x8*)&Bl[row * 40 + scol] = wv8;
    }
    __syncthreads();

    bf16x8 af[4], bfv[4];
#pragma unroll
    for (int t = 0; t < 4; ++t) {
      af[t]  = *(const bf16x8*)&Al[(wr + t * 16 + l15) * 40 + l4 * 8];
      bfv[t] = *(const bf16x8*)&Bl[(wc + t * 16 + l15) * 40 + l4 * 8];
    }
#pragma unroll
    for (int mt = 0; mt < 4; ++mt)
#pragma unroll
      for (int nt = 0; nt < 4; ++nt)
        acc[mt][nt] = mfma16(af[mt], bfv[nt], acc[mt][nt]);
    __syncthreads();
  }

#pragma unroll
  for (int mt = 0; mt < 4; ++mt)
#pragma unroll
    for (int nt = 0; nt < 4; ++nt)
#pragma unroll
      for (int r = 0; r < 4; ++r) {
        const size_t row = m0 + wr + mt * 16 + l4 * 4 + r;
        const size_t col = n0 + wc + nt * 16 + l15;
        if (CF32) ((float*)Cp)[row * N + col] = acc[mt][nt][r];
        else      ((bf16*)Cp)[row * N + col] = (bf16)acc[mt][nt][r];
      }
}

__global__ __launch_bounds__(256)
void k_gemm_qkv(const float* __restrict__ A0, const float* __restrict__ A1,
                const float* __restrict__ A2, const float* __restrict__ W0,
                const float* __restrict__ W1, const float* __restrict__ W2,
                bf16* __restrict__ C0, bf16* __restrict__ C1, bf16* __restrict__ C2) {
  const int z = blockIdx.z;
  const float* A = (z == 0) ? A0 : (z == 1) ? A1 : A2;
  const float* W = (z == 0) ? W0 : (z == 1) ? W1 : W2;
  bf16* C = (z == 0) ? C0 : (z == 1) ? C1 : C2;
  gemm_body<1, 0>(A, W, C, MM, DD, DD, blockIdx.x);
}

__global__ __launch_bounds__(256)
void k_gemm_out(const bf16* __restrict__ A, const float* __restrict__ W,
                float* __restrict__ C) {
  gemm_body<0, 1>(A, W, C, MM, DD, DD, blockIdx.x);
}

// ---------------- flash attention ----------------
// grid: (b*H + h)*16 + qt ; block 256 (4 waves), each wave 16 q-rows
__global__ __launch_bounds__(256)
void k_attn(const bf16* __restrict__ Qw, const bf16* __restrict__ Kw,
            const bf16* __restrict__ Vw, const unsigned* __restrict__ mb,
            bf16* __restrict__ Xw) {
  __shared__ bf16 Vl[64 * 72];        // transposed: Vl[d][k]
  __shared__ bf16 Pl[4 * 16 * 72];    // per-wave P tile [16 q][64 kv]
  const int tid = threadIdx.x, lane = tid & 63, wv = tid >> 6;
  const int l15 = lane & 15, l4 = lane >> 4;
  const int qt = blockIdx.x & 15;
  const int bh = blockIdx.x >> 4;
  const int h = bh & 15, b = bh >> 4;
  const int q0 = qt * 64 + wv * 16;

  const bf16* Qb = Qw + (size_t)(b * SS + q0 + l15) * DD + h * 64;
  bf16x8 qf[2];
  qf[0] = *(const bf16x8*)(Qb + l4 * 8);
  qf[1] = *(const bf16x8*)(Qb + 32 + l4 * 8);

  const bf16* Kb = Kw + (size_t)b * SS * DD + h * 64;
  const bf16* Vb = Vw + (size_t)b * SS * DD + h * 64;
  const unsigned* mrow = mb + (size_t)(b * SS + q0 + l4 * 4) * 32;

  f32x4 acco[4];
#pragma unroll
  for (int dt = 0; dt < 4; ++dt) acco[dt] = f32x4{0.f, 0.f, 0.f, 0.f};
  float mx[4], ssum[4];
#pragma unroll
  for (int r = 0; r < 4; ++r) { mx[r] = -1e30f; ssum[r] = 0.f; }

  bf16* Pw = &Pl[wv * 16 * 72];
  const int vd = tid & 63, vkb = tid >> 6;

  for (int kv = 0; kv < SS; kv += 64) {
    __syncthreads();  // previous tile's PV reads done before overwrite
    // stage V transposed (coalesced global: consecutive lanes read consecutive d)
#pragma unroll
    for (int i = 0; i < 16; ++i) {
      const int k = i * 4 + vkb;
      Vl[vd * 72 + k] = Vb[(size_t)(kv + k) * DD + vd];
    }
    // scores: QK^T for this wave's 16 q-rows x 64 kv-cols
    f32x4 sc[4];
#pragma unroll
    for (int st = 0; st < 4; ++st) {
      const bf16* kp = Kb + (size_t)(kv + st * 16 + l15) * DD;
      bf16x8 kf0 = *(const bf16x8*)(kp + l4 * 8);
      bf16x8 kf1 = *(const bf16x8*)(kp + 32 + l4 * 8);
      f32x4 s = f32x4{0.f, 0.f, 0.f, 0.f};
      s = mfma16(qf[0], kf0, s);
      s = mfma16(qf[1], kf1, s);
      sc[st] = s;
    }
    // mask words
    unsigned mw[4][2];
#pragma unroll
    for (int r = 0; r < 4; ++r) {
      mw[r][0] = mrow[r * 32 + (kv >> 5)];
      mw[r][1] = mrow[r * 32 + (kv >> 5) + 1];
    }
    float val[4][4];
#pragma unroll
    for (int st = 0; st < 4; ++st)
#pragma unroll
      for (int r = 0; r < 4; ++r) {
        const int bit = (mw[r][st >> 1] >> (l15 + ((st & 1) << 4))) & 1;
        val[st][r] = bit ? sc[st][r] * 0.125f : -1e9f;
      }
    // online softmax update
#pragma unroll
    for (int r = 0; r < 4; ++r) {
      float rm = fmaxf(fmaxf(val[0][r], val[1][r]), fmaxf(val[2][r], val[3][r]));
#pragma unroll
      for (int off = 1; off <= 8; off <<= 1) rm = fmaxf(rm, __shfl_xor(rm, off));
      const float mn = fmaxf(mx[r], rm);
      const float scal = __expf(mx[r] - mn);
      mx[r] = mn;
      ssum[r] *= scal;
#pragma unroll
      for (int dt = 0; dt < 4; ++dt) acco[dt][r] *= scal;
#pragma unroll
      for (int st = 0; st < 4; ++st) {
        const float p = __expf(val[st][r] - mn);
        ssum[r] += p;
        Pw[(l4 * 4 + r) * 72 + st * 16 + l15] = (bf16)p;
      }
    }
    __syncthreads();  // Vl + Pl ready
    // PV
#pragma unroll
    for (int kk = 0; kk < 2; ++kk) {
      bf16x8 pa = *(const bf16x8*)&Pw[l15 * 72 + kk * 32 + l4 * 8];
#pragma unroll
      for (int dt = 0; dt < 4; ++dt) {
        bf16x8 vb = *(const bf16x8*)&Vl[(dt * 16 + l15) * 72 + kk * 32 + l4 * 8];
        acco[dt] = mfma16(pa, vb, acco[dt]);
      }
    }
  }

  // normalize + write X[b][q][h*64+d]
#pragma unroll
  for (int r = 0; r < 4; ++r) {
#pragma unroll
    for (int off = 1; off <= 8; off <<= 1) ssum[r] += __shfl_xor(ssum[r], off);
  }
#pragma unroll
  for (int r = 0; r < 4; ++r) {
    const float inv = 1.0f / ssum[r];
#pragma unroll
    for (int dt = 0; dt < 4; ++dt) {
      Xw[(size_t)(b * SS + q0 + l4 * 4 + r) * DD + h * 64 + dt * 16 + l15] =
          (bf16)(acco[dt][r] * inv);
    }
  }
}

// ---------------- launch ----------------
extern "C" void kernel_launch(void* const* d_in, const int* in_sizes, int n_in,
                              void* d_out, int out_size, void* d_ws, size_t ws_size,
                              hipStream_t stream) {
  const float* q32 = (const float*)d_in[0];
  const float* k32 = (const float*)d_in[1];
  const float* v32 = (const float*)d_in[2];
  const int* mask = (const int*)d_in[3];
  const float* Wq = (const float*)d_in[4];
  const float* Wk = (const float*)d_in[5];
  const float* Wv = (const float*)d_in[6];
  const float* Wo = (const float*)d_in[7];
  float* out = (float*)d_out;

  bf16* Qb = (bf16*)d_ws;
  bf16* Kb = Qb + (size_t)MM * DD;
  bf16* Vb = Kb + (size_t)MM * DD;
  bf16* Xb = Vb + (size_t)MM * DD;
  unsigned* mbits = (unsigned*)(Xb + (size_t)MM * DD);

  k_mask_bits<<<BB * SS, 256, 0, stream>>>(mask, mbits);
  k_gemm_qkv<<<dim3((MM / 128) * (DD / 128), 1, 3), 256, 0, stream>>>(
      q32, k32, v32, Wq, Wk, Wv, Qb, Kb, Vb);
  k_attn<<<BB * HH * (SS / 64), 256, 0, stream>>>(Qb, Kb, Vb, mbits, Xb);
  k_gemm_out<<<(MM / 128) * (DD / 128), 256, 0, stream>>>(Xb, Wo, out);
}